// Round 6
// baseline (810.056 us; speedup 1.0000x reference)
//
#include <hip/hip_runtime.h>
#include <hip/hip_bf16.h>
#include <hip/hip_fp16.h>
#include <stdint.h>

#define NN 50000
#define NE 800000
#define HD 128
#define EPSN 1e-5f

typedef __hip_bfloat16 bf16;

__device__ __forceinline__ float us2f(unsigned short u) { return __uint_as_float((uint32_t)u << 16); }
__device__ __forceinline__ ushort f2us(float f) {
    bf16 b = __float2bfloat16(f);
    return *reinterpret_cast<ushort*>(&b);
}
__device__ __forceinline__ ushort f2h(float f) {
    __half h = __float2half(f);
    return *reinterpret_cast<ushort*>(&h);
}
__device__ __forceinline__ void h2x2f(uint32_t u, float& a, float& b) {
    union { uint32_t u; __half h[2]; } x;
    x.u = u;
    a = __half2float(x.h[0]);
    b = __half2float(x.h[1]);
}

// canonical fp32 parameter block offsets
#define O_X    0
#define O_CW   100000
#define O_CB   100256
#define O_LNG  100384
#define O_LNB  100512
#define O_BNG  100640
#define O_BNB  100768
#define O_W1   100896
#define O_B1   117280
#define O_W2   117408
#define O_B2   133792
#define O_W3   133920
#define O_B3   150304
#define O_F1W  150432
#define O_F1B  154528
#define O_F2W  154560
#define O_F2B  154624
#define O_TOT  154626

struct Ptrs { const void* p[17]; };

__device__ const int SEG_OFF[18] = {O_X, O_CW, O_CB, O_LNG, O_LNB, O_BNG, O_BNB,
                                    O_W1, O_B1, O_W2, O_B2, O_W3, O_B3,
                                    O_F1W, O_F1B, O_F2W, O_F2B, O_TOT};

// Edge accessor: isL=1 -> int64 storage (read low words), else int32.
__device__ __forceinline__ int eidx(const int* __restrict__ ei, int isL, int which, int e) {
    size_t base = (size_t)which * NE + e;
    return isL ? ei[2 * base] : ei[base];
}

// ---------------- dtype detection ----------------
// flags[0]: edge_index is int64.  flags[1]: floats are bf16.
__global__ void k_detect(const int* __restrict__ ei, const ushort* __restrict__ cw,
                         int* __restrict__ flags) {
    int t = threadIdx.x;   // 256 threads, 1 block
    int v = ei[2 * t + 1] | ei[1000000 + 2 * t + 1];
    int bad = 0;
    if (t < 128) {
        float val = us2f(cw[2 * t]);           // low half if f32, real weight if bf16
        bad = !(fabsf(val) <= 1.0f);           // NaN/Inf -> bad
    }
    for (int o = 32; o; o >>= 1) { v |= __shfl_xor(v, o); bad |= __shfl_xor(bad, o); }
    __shared__ int sv[4], sb[4];
    if ((t & 63) == 0) { sv[t >> 6] = v; sb[t >> 6] = bad; }
    __syncthreads();
    if (t == 0) {
        flags[0] = ((sv[0] | sv[1] | sv[2] | sv[3]) == 0) ? 1 : 0;
        flags[1] = ((sb[0] | sb[1] | sb[2] | sb[3]) == 0) ? 1 : 0;
    }
}

// ---------------- canonicalize all float inputs to fp32 ----------------
__global__ void k_conv(Ptrs ptrs, const int* __restrict__ flags, float* __restrict__ cp) {
    int i = blockIdx.x * 256 + threadIdx.x;
    if (i >= O_TOT) return;
    int s = 0;
    while (i >= SEG_OFF[s + 1]) s++;
    int local = i - SEG_OFF[s];
    const void* src = ptrs.p[s];
    cp[i] = flags[1] ? us2f(((const ushort*)src)[local]) : ((const float*)src)[local];
}

// ---------------- graph preprocessing ----------------

__global__ void k_init(int* __restrict__ deg, float* __restrict__ stats, int* __restrict__ cursor) {
    int i = blockIdx.x * 256 + threadIdx.x;
    if (i < NN) deg[i] = 1;           // self-loop
    if (i < 768) stats[i] = 0.f;      // 3 layers x 256 stats
    if (i == 0) *cursor = 0;
}

__global__ void k_deg(const int* __restrict__ ei, const int* __restrict__ flags,
                      int* __restrict__ deg) {
    int e = blockIdx.x * 256 + threadIdx.x;
    if (e < NE) atomicAdd(&deg[eidx(ei, flags[0], 1, e)], 1);
}

__global__ void k_dinv_alloc(const int* __restrict__ deg, float* __restrict__ dinv,
                             int* __restrict__ startA, int* __restrict__ curA,
                             int* __restrict__ cursor) {
    int i = blockIdx.x * 256 + threadIdx.x;
    if (i < NN) {
        int d = deg[i];
        dinv[i] = rsqrtf((float)d);
        int s = atomicAdd(cursor, d - 1);   // bucket order irrelevant for sums
        startA[i] = s;
        curA[i] = s;
    }
}

__global__ void k_fill(const int* __restrict__ ei, const int* __restrict__ flags,
                       const float* __restrict__ dinv, int* __restrict__ curA,
                       int* __restrict__ srow, float* __restrict__ snorm) {
    int e = blockIdx.x * 256 + threadIdx.x;
    if (e >= NE) return;
    int isL = flags[0];
    int r = eidx(ei, isL, 0, e);
    int c = eidx(ei, isL, 1, e);
    int p = atomicAdd(&curA[c], 1);
    srow[p] = r;
    snorm[p] = dinv[r] * dinv[c];
}

// ---------------- embed: relu(x @ coord_W + b) -> LayerNorm ----------------

__global__ void k_embed(const float* __restrict__ cp, float* __restrict__ h) {
    int node = (blockIdx.x * 256 + threadIdx.x) >> 6;
    int lane = threadIdx.x & 63;
    if (node >= NN) return;
    const float* X = cp + O_X;
    const float* CW = cp + O_CW;
    const float* CB = cp + O_CB;
    const float* LG = cp + O_LNG;
    const float* LB = cp + O_LNB;
    float x0 = X[node * 2], x1 = X[node * 2 + 1];
    int f0 = lane, f1 = lane + 64;
    float v0 = fmaxf(0.f, x0 * CW[f0] + x1 * CW[HD + f0] + CB[f0]);
    float v1 = fmaxf(0.f, x0 * CW[f1] + x1 * CW[HD + f1] + CB[f1]);
    float s = v0 + v1, q = v0 * v0 + v1 * v1;
    for (int o = 32; o; o >>= 1) { s += __shfl_xor(s, o); q += __shfl_xor(q, o); }
    float m = s * (1.f / HD);
    float var = q * (1.f / HD) - m * m;
    float r = rsqrtf(var + EPSN);
    h[(size_t)node * HD + f0] = (v0 - m) * r * LG[f0] + LB[f0];
    h[(size_t)node * HD + f1] = (v1 - m) * r * LG[f1] + LB[f1];
}

// ------- GEMM: t0 = h @ W (fp16 output) -------
// 32 nodes/block, 256 threads, 16 outputs/thread (4 nodes x 4 feats), k-blocked by 4.

__global__ __launch_bounds__(256) void k_gemm(const float* __restrict__ h,
                                              const float* __restrict__ Wf,
                                              ushort* __restrict__ t0h) {
    __shared__ float Wl[64 * HD];       // 32 KB (one k-phase)
    __shared__ float hl[32 * HD];       // 16 KB
    int t = threadIdx.x;
    int nodeBase = blockIdx.x * 32;
    const float4* h4 = (const float4*)h;
    float4* hl4 = (float4*)hl;
#pragma unroll
    for (int r = 0; r < 4; r++) {
        int idx = r * 256 + t;          // 0..1023
        int n = nodeBase + (idx >> 5);  // global node
        int c4 = idx & 31;              // float4 col
        hl4[idx] = (n < NN) ? h4[(size_t)n * 32 + c4] : make_float4(0.f, 0.f, 0.f, 0.f);
    }
    int fq = t & 31;                    // feature quad: feats 4fq..4fq+3
    int ng = t >> 5;                    // node group 0..7; nodes ng, ng+8, ng+16, ng+24
    float4 acc[4];
#pragma unroll
    for (int j = 0; j < 4; j++) acc[j] = make_float4(0.f, 0.f, 0.f, 0.f);
    const float4* Wl4 = (const float4*)Wl;
    for (int ph = 0; ph < 2; ph++) {
        __syncthreads();                // hl ready (ph=0); prior-phase Wl reads done (ph=1)
        const float4* Wg4 = (const float4*)(Wf + ph * 64 * HD);
        float4* Wld = (float4*)Wl;
#pragma unroll
        for (int r = 0; r < 8; r++) Wld[r * 256 + t] = Wg4[r * 256 + t];
        __syncthreads();
        for (int k4 = 0; k4 < 16; k4++) {
            int kb = k4 * 4;
            float4 w0 = Wl4[(kb + 0) * 32 + fq];
            float4 w1 = Wl4[(kb + 1) * 32 + fq];
            float4 w2 = Wl4[(kb + 2) * 32 + fq];
            float4 w3 = Wl4[(kb + 3) * 32 + fq];
#pragma unroll
            for (int j = 0; j < 4; j++) {
                float4 hv = hl4[(ng + 8 * j) * 32 + ph * 16 + k4];
                acc[j].x += hv.x * w0.x + hv.y * w1.x + hv.z * w2.x + hv.w * w3.x;
                acc[j].y += hv.x * w0.y + hv.y * w1.y + hv.z * w2.y + hv.w * w3.y;
                acc[j].z += hv.x * w0.z + hv.y * w1.z + hv.z * w2.z + hv.w * w3.z;
                acc[j].w += hv.x * w0.w + hv.y * w1.w + hv.z * w2.w + hv.w * w3.w;
            }
        }
    }
#pragma unroll
    for (int j = 0; j < 4; j++) {
        int n = nodeBase + ng + 8 * j;
        if (n < NN) {
            ushort4 o;
            o.x = f2h(acc[j].x); o.y = f2h(acc[j].y);
            o.z = f2h(acc[j].z); o.w = f2h(acc[j].w);
            ((ushort4*)(t0h + (size_t)n * HD))[fq] = o;
        }
    }
}

// ------- aggregate: agg[i] = dinv[i]^2*t0[i] + sum_in norm*t0[row]; fused BN stats -------
// t0 gathered as packed fp16 (2 feats/thread, 64 threads/node, 4 nodes/block-iter);
// unroll-8 neighbor loop keeps 8 independent gathers in flight.

__global__ __launch_bounds__(256) void k_agg(const uint32_t* __restrict__ t0v,
                                             const int* __restrict__ srow,
                                             const float* __restrict__ snorm,
                                             const int* __restrict__ startA,
                                             const int* __restrict__ deg,
                                             const float* __restrict__ dinv,
                                             const float* __restrict__ bias,
                                             float* __restrict__ agg,
                                             float* __restrict__ stats) {
    int t = threadIdx.x;
    int f2 = t & 63;               // feats 2*f2, 2*f2+1
    int g = t >> 6;                // node subgroup 0..3
    float b0 = bias[2 * f2], b1 = bias[2 * f2 + 1];
    float s1a = 0.f, s1b = 0.f, s2a = 0.f, s2b = 0.f;
    for (int grp = blockIdx.x; grp * 4 < NN; grp += gridDim.x) {
        int i = grp * 4 + g;
        if (i < NN) {
            float di = dinv[i];
            float sx, sy;
            h2x2f(t0v[(size_t)i * 64 + f2], sx, sy);
            float acc0 = di * di * sx, acc1 = di * di * sy;   // self-loop term
            int s = startA[i];
            int cnt = deg[i] - 1;
            int j = 0;
            for (; j + 8 <= cnt; j += 8) {
                uint32_t v[8]; float w[8];
#pragma unroll
                for (int u = 0; u < 8; u++) {
                    int r = srow[s + j + u];
                    w[u] = snorm[s + j + u];
                    v[u] = t0v[(size_t)r * 64 + f2];
                }
#pragma unroll
                for (int u = 0; u < 8; u++) {
                    float a, b; h2x2f(v[u], a, b);
                    acc0 += w[u] * a; acc1 += w[u] * b;
                }
            }
            for (; j < cnt; j++) {
                int r = srow[s + j];
                float w = snorm[s + j];
                float a, b; h2x2f(t0v[(size_t)r * 64 + f2], a, b);
                acc0 += w * a; acc1 += w * b;
            }
            ((float2*)(agg + (size_t)i * HD))[f2] = make_float2(acc0, acc1);
            float y0 = fmaxf(0.f, acc0 + b0);
            float y1 = fmaxf(0.f, acc1 + b1);
            s1a += y0; s1b += y1;
            s2a += y0 * y0; s2b += y1 * y1;
        }
    }
    __shared__ float ls[4][256];
    ls[0][t] = s1a; ls[1][t] = s1b; ls[2][t] = s2a; ls[3][t] = s2b;
    __syncthreads();
    if (t < 64) {
        float a0 = ls[0][t] + ls[0][t + 64] + ls[0][t + 128] + ls[0][t + 192];
        float a1 = ls[1][t] + ls[1][t + 64] + ls[1][t + 128] + ls[1][t + 192];
        float q0 = ls[2][t] + ls[2][t + 64] + ls[2][t + 128] + ls[2][t + 192];
        float q1 = ls[3][t] + ls[3][t + 64] + ls[3][t + 128] + ls[3][t + 192];
        atomicAdd(&stats[2 * t], a0);
        atomicAdd(&stats[2 * t + 1], a1);
        atomicAdd(&stats[128 + 2 * t], q0);
        atomicAdd(&stats[128 + 2 * t + 1], q1);
    }
}

// ------- BN apply + residual + InstanceNorm (in-place on h) -------

__global__ void k_post(const float* __restrict__ agg, const float* __restrict__ stats,
                       const float* __restrict__ bias, const float* __restrict__ bng,
                       const float* __restrict__ bnb, float* __restrict__ h) {
    int node = (blockIdx.x * 256 + threadIdx.x) >> 6;
    int lane = threadIdx.x & 63;
    if (node >= NN) return;
    const float invN = 1.f / NN;
    int f0 = lane, f1 = lane + 64;
    float m0 = stats[f0] * invN, m1 = stats[f1] * invN;
    float v0 = stats[128 + f0] * invN - m0 * m0;
    float v1 = stats[128 + f1] * invN - m1 * m1;
    float sc0 = bng[f0] * rsqrtf(v0 + EPSN);
    float sc1 = bng[f1] * rsqrtf(v1 + EPSN);
    float sh0 = bnb[f0] - m0 * sc0;
    float sh1 = bnb[f1] - m1 * sc1;
    size_t base = (size_t)node * HD;
    float y0 = fmaxf(0.f, agg[base + f0] + bias[f0]);
    float y1 = fmaxf(0.f, agg[base + f1] + bias[f1]);
    float u0 = y0 * sc0 + sh0 + h[base + f0];
    float u1 = y1 * sc1 + sh1 + h[base + f1];
    float s = u0 + u1, q = u0 * u0 + u1 * u1;
    for (int o = 32; o; o >>= 1) { s += __shfl_xor(s, o); q += __shfl_xor(q, o); }
    float m = s * (1.f / HD);
    float var = q * (1.f / HD) - m * m;
    float r = rsqrtf(var + EPSN);
    h[base + f0] = (u0 - m) * r;
    h[base + f1] = (u1 - m) * r;
}

// ------- head: relu(h @ fc1 + b) -> tanh(@ fc2 + b); output dtype per flag -------

__global__ __launch_bounds__(256) void k_head(const float* __restrict__ h,
                                              const float* __restrict__ cp,
                                              const int* __restrict__ flags,
                                              void* __restrict__ outv) {
    __shared__ float W1[HD * 32];   // 16 KB, flat [k][f]
    __shared__ float B1[32], W2[64], B2[2];
    int t = threadIdx.x;
    const float* f1W = cp + O_F1W;
    for (int r = 0; r < 16; r++) W1[r * 256 + t] = f1W[r * 256 + t];
    if (t < 32) B1[t] = cp[O_F1B + t];
    if (t < 64) W2[t] = cp[O_F2W + t];
    if (t < 2) B2[t] = cp[O_F2B + t];
    __syncthreads();
    int i = blockIdx.x * 256 + t;
    if (i >= NN) return;
    float a[32];
#pragma unroll
    for (int f = 0; f < 32; f++) a[f] = B1[f];
    const float4* hr = (const float4*)(h + (size_t)i * HD);
    for (int c = 0; c < 4; c++) {
        float hk[32];
#pragma unroll
        for (int qd = 0; qd < 8; qd++) {
            float4 v = hr[c * 8 + qd];
            hk[4 * qd] = v.x; hk[4 * qd + 1] = v.y; hk[4 * qd + 2] = v.z; hk[4 * qd + 3] = v.w;
        }
#pragma unroll
        for (int kk = 0; kk < 32; kk++) {
            float hv = hk[kk];
            const float4* wr = (const float4*)(W1 + (c * 32 + kk) * 32);
#pragma unroll
            for (int qd = 0; qd < 8; qd++) {
                float4 w = wr[qd];
                a[4 * qd] += hv * w.x; a[4 * qd + 1] += hv * w.y;
                a[4 * qd + 2] += hv * w.z; a[4 * qd + 3] += hv * w.w;
            }
        }
    }
    float o0 = B2[0], o1 = B2[1];
#pragma unroll
    for (int f = 0; f < 32; f++) {
        float av = fmaxf(0.f, a[f]);
        o0 += av * W2[f * 2];
        o1 += av * W2[f * 2 + 1];
    }
    o0 = tanhf(o0); o1 = tanhf(o1);
    if (flags[1]) {
        ushort* ob = (ushort*)outv;
        ob[i * 2] = f2us(o0);
        ob[i * 2 + 1] = f2us(o1);
    } else {
        float* of = (float*)outv;
        of[i * 2] = o0;
        of[i * 2 + 1] = o1;
    }
}

// ---------------- launch ----------------

extern "C" void kernel_launch(void* const* d_in, const int* in_sizes, int n_in,
                              void* d_out, int out_size, void* d_ws, size_t ws_size,
                              hipStream_t stream) {
    const int* ei = (const int*)d_in[1];

    Ptrs ptrs;
    ptrs.p[0] = d_in[0];                                  // x
    for (int s = 1; s < 17; s++) ptrs.p[s] = d_in[s + 1]; // coord_W .. fc2_b

    char* wsp = (char*)d_ws;
    size_t off = 0;
    auto alloc = [&](size_t bytes) {
        void* p = wsp + off;
        off += (bytes + 255) & ~(size_t)255;
        return p;
    };
    float* cp     = (float*)alloc((size_t)O_TOT * 4);       // 0.62 MB canonical fp32 params
    float* h      = (float*)alloc((size_t)NN * HD * 4);     // 25.6 MB
    ushort* t0h   = (ushort*)alloc((size_t)NN * HD * 2);    // 12.8 MB fp16
    float* agg    = (float*)alloc((size_t)NN * HD * 4);     // 25.6 MB
    int* deg      = (int*)alloc((size_t)NN * 4);
    float* dinv   = (float*)alloc((size_t)NN * 4);
    int* srow     = (int*)alloc((size_t)NE * 4);
    float* snorm  = (float*)alloc((size_t)NE * 4);
    int* startA   = (int*)alloc((size_t)NN * 4);
    int* curA     = (int*)alloc((size_t)NN * 4);
    float* stats  = (float*)alloc(3 * 256 * 4);
    int* cursor   = (int*)alloc(256);
    int* flags    = (int*)alloc(256);

    const int BN_NODE = (NN + 255) / 256;   // 196
    const int BN_EDGE = (NE + 255) / 256;   // 3125
    const int BN_CONV = (O_TOT + 255) / 256;

    const float* W[3] = {cp + O_W1, cp + O_W2, cp + O_W3};
    const float* B[3] = {cp + O_B1, cp + O_B2, cp + O_B3};

    k_detect<<<1, 256, 0, stream>>>(ei, (const ushort*)d_in[2], flags);
    k_conv<<<BN_CONV, 256, 0, stream>>>(ptrs, flags, cp);
    k_init<<<BN_NODE, 256, 0, stream>>>(deg, stats, cursor);
    k_deg<<<BN_EDGE, 256, 0, stream>>>(ei, flags, deg);
    k_dinv_alloc<<<BN_NODE, 256, 0, stream>>>(deg, dinv, startA, curA, cursor);
    k_fill<<<BN_EDGE, 256, 0, stream>>>(ei, flags, dinv, curA, srow, snorm);
    k_embed<<<NN / 4, 256, 0, stream>>>(cp, h);

    for (int l = 0; l < 3; l++) {
        k_gemm<<<(NN + 31) / 32, 256, 0, stream>>>(h, W[l], t0h);
        k_agg<<<2048, 256, 0, stream>>>((const uint32_t*)t0h, srow, snorm, startA, deg,
                                        dinv, B[l], agg, stats + 256 * l);
        k_post<<<NN / 4, 256, 0, stream>>>(agg, stats + 256 * l, B[l],
                                           cp + O_BNG, cp + O_BNB, h);
    }
    k_head<<<BN_NODE, 256, 0, stream>>>(h, cp, flags, d_out);
}

// Round 7
// 719.586 us; speedup vs baseline: 1.1257x; 1.1257x over previous
//
#include <hip/hip_runtime.h>
#include <hip/hip_bf16.h>
#include <hip/hip_fp16.h>
#include <stdint.h>

#define NN 50000
#define NE 800000
#define HD 128
#define EPSN 1e-5f

typedef __hip_bfloat16 bf16;

__device__ __forceinline__ float us2f(unsigned short u) { return __uint_as_float((uint32_t)u << 16); }
__device__ __forceinline__ ushort f2us(float f) {
    bf16 b = __float2bfloat16(f);
    return *reinterpret_cast<ushort*>(&b);
}
__device__ __forceinline__ ushort f2h(float f) {
    __half h = __float2half(f);
    return *reinterpret_cast<ushort*>(&h);
}
__device__ __forceinline__ float h2f(ushort u) {
    __half h = *reinterpret_cast<__half*>(&u);
    return __half2float(h);
}

// canonical fp32 parameter block offsets
#define O_X    0
#define O_CW   100000
#define O_CB   100256
#define O_LNG  100384
#define O_LNB  100512
#define O_BNG  100640
#define O_BNB  100768
#define O_W1   100896
#define O_B1   117280
#define O_W2   117408
#define O_B2   133792
#define O_W3   133920
#define O_B3   150304
#define O_F1W  150432
#define O_F1B  154528
#define O_F2W  154560
#define O_F2B  154624
#define O_TOT  154626

struct Ptrs { const void* p[17]; };

__device__ const int SEG_OFF[18] = {O_X, O_CW, O_CB, O_LNG, O_LNB, O_BNG, O_BNB,
                                    O_W1, O_B1, O_W2, O_B2, O_W3, O_B3,
                                    O_F1W, O_F1B, O_F2W, O_F2B, O_TOT};

// Edge accessor: isL=1 -> int64 storage (read low words), else int32.
__device__ __forceinline__ int eidx(const int* __restrict__ ei, int isL, int which, int e) {
    size_t base = (size_t)which * NE + e;
    return isL ? ei[2 * base] : ei[base];
}

// ---------------- dtype detection ----------------
// flags[0]: edge_index is int64.  flags[1]: floats are bf16.
__global__ void k_detect(const int* __restrict__ ei, const ushort* __restrict__ cw,
                         int* __restrict__ flags) {
    int t = threadIdx.x;   // 256 threads, 1 block
    int v = ei[2 * t + 1] | ei[1000000 + 2 * t + 1];
    int bad = 0;
    if (t < 128) {
        float val = us2f(cw[2 * t]);           // low half if f32, real weight if bf16
        bad = !(fabsf(val) <= 1.0f);           // NaN/Inf -> bad
    }
    for (int o = 32; o; o >>= 1) { v |= __shfl_xor(v, o); bad |= __shfl_xor(bad, o); }
    __shared__ int sv[4], sb[4];
    if ((t & 63) == 0) { sv[t >> 6] = v; sb[t >> 6] = bad; }
    __syncthreads();
    if (t == 0) {
        flags[0] = ((sv[0] | sv[1] | sv[2] | sv[3]) == 0) ? 1 : 0;
        flags[1] = ((sb[0] | sb[1] | sb[2] | sb[3]) == 0) ? 1 : 0;
    }
}

// ---------------- canonicalize all float inputs to fp32 ----------------
__global__ void k_conv(Ptrs ptrs, const int* __restrict__ flags, float* __restrict__ cp) {
    int i = blockIdx.x * 256 + threadIdx.x;
    if (i >= O_TOT) return;
    int s = 0;
    while (i >= SEG_OFF[s + 1]) s++;
    int local = i - SEG_OFF[s];
    const void* src = ptrs.p[s];
    cp[i] = flags[1] ? us2f(((const ushort*)src)[local]) : ((const float*)src)[local];
}

// ---------------- graph preprocessing ----------------

__global__ void k_init(int* __restrict__ deg, float* __restrict__ stats, int* __restrict__ cursor) {
    int i = blockIdx.x * 256 + threadIdx.x;
    if (i < NN) deg[i] = 1;           // self-loop
    if (i < 768) stats[i] = 0.f;      // 3 layers x 256 stats
    if (i == 0) *cursor = 0;
}

__global__ void k_deg(const int* __restrict__ ei, const int* __restrict__ flags,
                      int* __restrict__ deg) {
    int e = blockIdx.x * 256 + threadIdx.x;
    if (e < NE) atomicAdd(&deg[eidx(ei, flags[0], 1, e)], 1);
}

__global__ void k_dinv_alloc(const int* __restrict__ deg, float* __restrict__ dinv,
                             int* __restrict__ startA, int* __restrict__ curA,
                             int* __restrict__ cursor) {
    int i = blockIdx.x * 256 + threadIdx.x;
    if (i < NN) {
        int d = deg[i];
        dinv[i] = rsqrtf((float)d);
        int s = atomicAdd(cursor, d - 1);   // bucket order irrelevant for sums
        startA[i] = s;
        curA[i] = s;
    }
}

__global__ void k_fill(const int* __restrict__ ei, const int* __restrict__ flags,
                       const float* __restrict__ dinv, int* __restrict__ curA,
                       int* __restrict__ srow, float* __restrict__ snorm) {
    int e = blockIdx.x * 256 + threadIdx.x;
    if (e >= NE) return;
    int isL = flags[0];
    int r = eidx(ei, isL, 0, e);
    int c = eidx(ei, isL, 1, e);
    int p = atomicAdd(&curA[c], 1);
    srow[p] = r;
    snorm[p] = dinv[r] * dinv[c];
}

// ---------------- embed: relu(x @ coord_W + b) -> LayerNorm ----------------

__global__ void k_embed(const float* __restrict__ cp, float* __restrict__ h) {
    int node = (blockIdx.x * 256 + threadIdx.x) >> 6;
    int lane = threadIdx.x & 63;
    if (node >= NN) return;
    const float* X = cp + O_X;
    const float* CW = cp + O_CW;
    const float* CB = cp + O_CB;
    const float* LG = cp + O_LNG;
    const float* LB = cp + O_LNB;
    float x0 = X[node * 2], x1 = X[node * 2 + 1];
    int f0 = lane, f1 = lane + 64;
    float v0 = fmaxf(0.f, x0 * CW[f0] + x1 * CW[HD + f0] + CB[f0]);
    float v1 = fmaxf(0.f, x0 * CW[f1] + x1 * CW[HD + f1] + CB[f1]);
    float s = v0 + v1, q = v0 * v0 + v1 * v1;
    for (int o = 32; o; o >>= 1) { s += __shfl_xor(s, o); q += __shfl_xor(q, o); }
    float m = s * (1.f / HD);
    float var = q * (1.f / HD) - m * m;
    float r = rsqrtf(var + EPSN);
    h[(size_t)node * HD + f0] = (v0 - m) * r * LG[f0] + LB[f0];
    h[(size_t)node * HD + f1] = (v1 - m) * r * LG[f1] + LB[f1];
}

// ------- GEMM: t0 = h @ W (fp16 output) -------
// 32 nodes/block, 256 threads, 16 outputs/thread (4 nodes x 4 feats), k-blocked by 4.

__global__ __launch_bounds__(256) void k_gemm(const float* __restrict__ h,
                                              const float* __restrict__ Wf,
                                              ushort* __restrict__ t0h) {
    __shared__ float Wl[64 * HD];       // 32 KB (one k-phase)
    __shared__ float hl[32 * HD];       // 16 KB
    int t = threadIdx.x;
    int nodeBase = blockIdx.x * 32;
    const float4* h4 = (const float4*)h;
    float4* hl4 = (float4*)hl;
#pragma unroll
    for (int r = 0; r < 4; r++) {
        int idx = r * 256 + t;          // 0..1023
        int n = nodeBase + (idx >> 5);  // global node
        int c4 = idx & 31;              // float4 col
        hl4[idx] = (n < NN) ? h4[(size_t)n * 32 + c4] : make_float4(0.f, 0.f, 0.f, 0.f);
    }
    int fq = t & 31;                    // feature quad: feats 4fq..4fq+3
    int ng = t >> 5;                    // node group 0..7; nodes ng, ng+8, ng+16, ng+24
    float4 acc[4];
#pragma unroll
    for (int j = 0; j < 4; j++) acc[j] = make_float4(0.f, 0.f, 0.f, 0.f);
    const float4* Wl4 = (const float4*)Wl;
    for (int ph = 0; ph < 2; ph++) {
        __syncthreads();                // hl ready (ph=0); prior-phase Wl reads done (ph=1)
        const float4* Wg4 = (const float4*)(Wf + ph * 64 * HD);
        float4* Wld = (float4*)Wl;
#pragma unroll
        for (int r = 0; r < 8; r++) Wld[r * 256 + t] = Wg4[r * 256 + t];
        __syncthreads();
        for (int k4 = 0; k4 < 16; k4++) {
            int kb = k4 * 4;
            float4 w0 = Wl4[(kb + 0) * 32 + fq];
            float4 w1 = Wl4[(kb + 1) * 32 + fq];
            float4 w2 = Wl4[(kb + 2) * 32 + fq];
            float4 w3 = Wl4[(kb + 3) * 32 + fq];
#pragma unroll
            for (int j = 0; j < 4; j++) {
                float4 hv = hl4[(ng + 8 * j) * 32 + ph * 16 + k4];
                acc[j].x += hv.x * w0.x + hv.y * w1.x + hv.z * w2.x + hv.w * w3.x;
                acc[j].y += hv.x * w0.y + hv.y * w1.y + hv.z * w2.y + hv.w * w3.y;
                acc[j].z += hv.x * w0.z + hv.y * w1.z + hv.z * w2.z + hv.w * w3.z;
                acc[j].w += hv.x * w0.w + hv.y * w1.w + hv.z * w2.w + hv.w * w3.w;
            }
        }
    }
#pragma unroll
    for (int j = 0; j < 4; j++) {
        int n = nodeBase + ng + 8 * j;
        if (n < NN) {
            ushort4 o;
            o.x = f2h(acc[j].x); o.y = f2h(acc[j].y);
            o.z = f2h(acc[j].z); o.w = f2h(acc[j].w);
            ((ushort4*)(t0h + (size_t)n * HD))[fq] = o;
        }
    }
}

// ------- aggregate: agg[i] = dinv[i]^2*t0[i] + sum_in norm*t0[row]; fused BN stats -------
// round-5 issue structure (128 threads/node = 2 waves, 2 nodes/block-iter, unroll 4);
// payload is fp16 ushort (1 x 128B line per wave per edge).

__global__ __launch_bounds__(256) void k_agg(const ushort* __restrict__ t0h,
                                             const int* __restrict__ srow,
                                             const float* __restrict__ snorm,
                                             const int* __restrict__ startA,
                                             const int* __restrict__ deg,
                                             const float* __restrict__ dinv,
                                             const float* __restrict__ bias,
                                             float* __restrict__ agg,
                                             float* __restrict__ stats) {
    int t = threadIdx.x;
    int f = t & 127;
    int half = t >> 7;
    float bs = bias[f];
    float rs1 = 0.f, rs2 = 0.f;
    for (int pair = blockIdx.x; pair * 2 < NN; pair += gridDim.x) {
        int i = pair * 2 + half;
        if (i < NN) {
            float di = dinv[i];
            float acc = di * di * h2f(t0h[(size_t)i * HD + f]);   // self-loop term
            int s = startA[i];
            int cnt = deg[i] - 1;
            float a0 = 0.f, a1 = 0.f, a2 = 0.f, a3 = 0.f;
            int j = 0;
            for (; j + 4 <= cnt; j += 4) {
                int r0 = srow[s + j];     float w0 = snorm[s + j];
                int r1 = srow[s + j + 1]; float w1 = snorm[s + j + 1];
                int r2 = srow[s + j + 2]; float w2 = snorm[s + j + 2];
                int r3 = srow[s + j + 3]; float w3 = snorm[s + j + 3];
                a0 += w0 * h2f(t0h[(size_t)r0 * HD + f]);
                a1 += w1 * h2f(t0h[(size_t)r1 * HD + f]);
                a2 += w2 * h2f(t0h[(size_t)r2 * HD + f]);
                a3 += w3 * h2f(t0h[(size_t)r3 * HD + f]);
            }
            for (; j < cnt; j++) {
                int r = srow[s + j];
                acc += snorm[s + j] * h2f(t0h[(size_t)r * HD + f]);
            }
            acc += (a0 + a1) + (a2 + a3);
            agg[(size_t)i * HD + f] = acc;
            float y = fmaxf(0.f, acc + bs);
            rs1 += y;
            rs2 += y * y;
        }
    }
    __shared__ float l1[256], l2[256];
    l1[t] = rs1; l2[t] = rs2;
    __syncthreads();
    if (t < 128) {
        atomicAdd(&stats[t], l1[t] + l1[t + 128]);
        atomicAdd(&stats[128 + t], l2[t] + l2[t + 128]);
    }
}

// ------- BN apply + residual + InstanceNorm (in-place on h) -------

__global__ void k_post(const float* __restrict__ agg, const float* __restrict__ stats,
                       const float* __restrict__ bias, const float* __restrict__ bng,
                       const float* __restrict__ bnb, float* __restrict__ h) {
    int node = (blockIdx.x * 256 + threadIdx.x) >> 6;
    int lane = threadIdx.x & 63;
    if (node >= NN) return;
    const float invN = 1.f / NN;
    int f0 = lane, f1 = lane + 64;
    float m0 = stats[f0] * invN, m1 = stats[f1] * invN;
    float v0 = stats[128 + f0] * invN - m0 * m0;
    float v1 = stats[128 + f1] * invN - m1 * m1;
    float sc0 = bng[f0] * rsqrtf(v0 + EPSN);
    float sc1 = bng[f1] * rsqrtf(v1 + EPSN);
    float sh0 = bnb[f0] - m0 * sc0;
    float sh1 = bnb[f1] - m1 * sc1;
    size_t base = (size_t)node * HD;
    float y0 = fmaxf(0.f, agg[base + f0] + bias[f0]);
    float y1 = fmaxf(0.f, agg[base + f1] + bias[f1]);
    float u0 = y0 * sc0 + sh0 + h[base + f0];
    float u1 = y1 * sc1 + sh1 + h[base + f1];
    float s = u0 + u1, q = u0 * u0 + u1 * u1;
    for (int o = 32; o; o >>= 1) { s += __shfl_xor(s, o); q += __shfl_xor(q, o); }
    float m = s * (1.f / HD);
    float var = q * (1.f / HD) - m * m;
    float r = rsqrtf(var + EPSN);
    h[base + f0] = (u0 - m) * r;
    h[base + f1] = (u1 - m) * r;
}

// ------- head: relu(h @ fc1 + b) -> tanh(@ fc2 + b); output dtype per flag -------

__global__ __launch_bounds__(256) void k_head(const float* __restrict__ h,
                                              const float* __restrict__ cp,
                                              const int* __restrict__ flags,
                                              void* __restrict__ outv) {
    __shared__ float W1[HD * 32];   // 16 KB, flat [k][f]
    __shared__ float B1[32], W2[64], B2[2];
    int t = threadIdx.x;
    const float* f1W = cp + O_F1W;
    for (int r = 0; r < 16; r++) W1[r * 256 + t] = f1W[r * 256 + t];
    if (t < 32) B1[t] = cp[O_F1B + t];
    if (t < 64) W2[t] = cp[O_F2W + t];
    if (t < 2) B2[t] = cp[O_F2B + t];
    __syncthreads();
    int i = blockIdx.x * 256 + t;
    if (i >= NN) return;
    float a[32];
#pragma unroll
    for (int f = 0; f < 32; f++) a[f] = B1[f];
    const float4* hr = (const float4*)(h + (size_t)i * HD);
    for (int c = 0; c < 4; c++) {
        float hk[32];
#pragma unroll
        for (int qd = 0; qd < 8; qd++) {
            float4 v = hr[c * 8 + qd];
            hk[4 * qd] = v.x; hk[4 * qd + 1] = v.y; hk[4 * qd + 2] = v.z; hk[4 * qd + 3] = v.w;
        }
#pragma unroll
        for (int kk = 0; kk < 32; kk++) {
            float hv = hk[kk];
            const float4* wr = (const float4*)(W1 + (c * 32 + kk) * 32);
#pragma unroll
            for (int qd = 0; qd < 8; qd++) {
                float4 w = wr[qd];
                a[4 * qd] += hv * w.x; a[4 * qd + 1] += hv * w.y;
                a[4 * qd + 2] += hv * w.z; a[4 * qd + 3] += hv * w.w;
            }
        }
    }
    float o0 = B2[0], o1 = B2[1];
#pragma unroll
    for (int f = 0; f < 32; f++) {
        float av = fmaxf(0.f, a[f]);
        o0 += av * W2[f * 2];
        o1 += av * W2[f * 2 + 1];
    }
    o0 = tanhf(o0); o1 = tanhf(o1);
    if (flags[1]) {
        ushort* ob = (ushort*)outv;
        ob[i * 2] = f2us(o0);
        ob[i * 2 + 1] = f2us(o1);
    } else {
        float* of = (float*)outv;
        of[i * 2] = o0;
        of[i * 2 + 1] = o1;
    }
}

// ---------------- launch ----------------

extern "C" void kernel_launch(void* const* d_in, const int* in_sizes, int n_in,
                              void* d_out, int out_size, void* d_ws, size_t ws_size,
                              hipStream_t stream) {
    const int* ei = (const int*)d_in[1];

    Ptrs ptrs;
    ptrs.p[0] = d_in[0];                                  // x
    for (int s = 1; s < 17; s++) ptrs.p[s] = d_in[s + 1]; // coord_W .. fc2_b

    char* wsp = (char*)d_ws;
    size_t off = 0;
    auto alloc = [&](size_t bytes) {
        void* p = wsp + off;
        off += (bytes + 255) & ~(size_t)255;
        return p;
    };
    float* cp     = (float*)alloc((size_t)O_TOT * 4);       // 0.62 MB canonical fp32 params
    float* h      = (float*)alloc((size_t)NN * HD * 4);     // 25.6 MB
    ushort* t0h   = (ushort*)alloc((size_t)NN * HD * 2);    // 12.8 MB fp16
    float* agg    = (float*)alloc((size_t)NN * HD * 4);     // 25.6 MB
    int* deg      = (int*)alloc((size_t)NN * 4);
    float* dinv   = (float*)alloc((size_t)NN * 4);
    int* srow     = (int*)alloc((size_t)NE * 4);
    float* snorm  = (float*)alloc((size_t)NE * 4);
    int* startA   = (int*)alloc((size_t)NN * 4);
    int* curA     = (int*)alloc((size_t)NN * 4);
    float* stats  = (float*)alloc(3 * 256 * 4);
    int* cursor   = (int*)alloc(256);
    int* flags    = (int*)alloc(256);

    const int BN_NODE = (NN + 255) / 256;   // 196
    const int BN_EDGE = (NE + 255) / 256;   // 3125
    const int BN_CONV = (O_TOT + 255) / 256;

    const float* W[3] = {cp + O_W1, cp + O_W2, cp + O_W3};
    const float* B[3] = {cp + O_B1, cp + O_B2, cp + O_B3};

    k_detect<<<1, 256, 0, stream>>>(ei, (const ushort*)d_in[2], flags);
    k_conv<<<BN_CONV, 256, 0, stream>>>(ptrs, flags, cp);
    k_init<<<BN_NODE, 256, 0, stream>>>(deg, stats, cursor);
    k_deg<<<BN_EDGE, 256, 0, stream>>>(ei, flags, deg);
    k_dinv_alloc<<<BN_NODE, 256, 0, stream>>>(deg, dinv, startA, curA, cursor);
    k_fill<<<BN_EDGE, 256, 0, stream>>>(ei, flags, dinv, curA, srow, snorm);
    k_embed<<<NN / 4, 256, 0, stream>>>(cp, h);

    for (int l = 0; l < 3; l++) {
        k_gemm<<<(NN + 31) / 32, 256, 0, stream>>>(h, W[l], t0h);
        k_agg<<<2048, 256, 0, stream>>>(t0h, srow, snorm, startA, deg,
                                        dinv, B[l], agg, stats + 256 * l);
        k_post<<<NN / 4, 256, 0, stream>>>(agg, stats + 256 * l, B[l],
                                           cp + O_BNG, cp + O_BNB, h);
    }
    k_head<<<BN_NODE, 256, 0, stream>>>(h, cp, flags, d_out);
}

// Round 8
// 690.211 us; speedup vs baseline: 1.1736x; 1.0426x over previous
//
#include <hip/hip_runtime.h>
#include <hip/hip_bf16.h>
#include <hip/hip_fp16.h>
#include <stdint.h>

#define NN 50000
#define NE 800000
#define HD 128
#define EPSN 1e-5f
#define CAP 1152000   // padded CSR capacity: NE + NN*7 rounded up

typedef __hip_bfloat16 bf16;

__device__ __forceinline__ float us2f(unsigned short u) { return __uint_as_float((uint32_t)u << 16); }
__device__ __forceinline__ ushort f2us(float f) {
    bf16 b = __float2bfloat16(f);
    return *reinterpret_cast<ushort*>(&b);
}
__device__ __forceinline__ ushort f2h(float f) {
    __half h = __float2half(f);
    return *reinterpret_cast<ushort*>(&h);
}
__device__ __forceinline__ float h2f(ushort u) {
    __half h = *reinterpret_cast<__half*>(&u);
    return __half2float(h);
}

// canonical fp32 parameter block offsets
#define O_X    0
#define O_CW   100000
#define O_CB   100256
#define O_LNG  100384
#define O_LNB  100512
#define O_BNG  100640
#define O_BNB  100768
#define O_W1   100896
#define O_B1   117280
#define O_W2   117408
#define O_B2   133792
#define O_W3   133920
#define O_B3   150304
#define O_F1W  150432
#define O_F1B  154528
#define O_F2W  154560
#define O_F2B  154624
#define O_TOT  154626

struct Ptrs { const void* p[17]; };

__device__ const int SEG_OFF[18] = {O_X, O_CW, O_CB, O_LNG, O_LNB, O_BNG, O_BNB,
                                    O_W1, O_B1, O_W2, O_B2, O_W3, O_B3,
                                    O_F1W, O_F1B, O_F2W, O_F2B, O_TOT};

// Edge accessor: isL=1 -> int64 storage (read low words), else int32.
__device__ __forceinline__ int eidx(const int* __restrict__ ei, int isL, int which, int e) {
    size_t base = (size_t)which * NE + e;
    return isL ? ei[2 * base] : ei[base];
}

// ---------------- dtype detection ----------------
__global__ void k_detect(const int* __restrict__ ei, const ushort* __restrict__ cw,
                         int* __restrict__ flags) {
    int t = threadIdx.x;   // 256 threads, 1 block
    int v = ei[2 * t + 1] | ei[1000000 + 2 * t + 1];
    int bad = 0;
    if (t < 128) {
        float val = us2f(cw[2 * t]);           // low half if f32, real weight if bf16
        bad = !(fabsf(val) <= 1.0f);           // NaN/Inf -> bad
    }
    for (int o = 32; o; o >>= 1) { v |= __shfl_xor(v, o); bad |= __shfl_xor(bad, o); }
    __shared__ int sv[4], sb[4];
    if ((t & 63) == 0) { sv[t >> 6] = v; sb[t >> 6] = bad; }
    __syncthreads();
    if (t == 0) {
        flags[0] = ((sv[0] | sv[1] | sv[2] | sv[3]) == 0) ? 1 : 0;
        flags[1] = ((sb[0] | sb[1] | sb[2] | sb[3]) == 0) ? 1 : 0;
    }
}

// ---------------- canonicalize all float inputs to fp32 ----------------
__global__ void k_conv(Ptrs ptrs, const int* __restrict__ flags, float* __restrict__ cp) {
    int i = blockIdx.x * 256 + threadIdx.x;
    if (i >= O_TOT) return;
    int s = 0;
    while (i >= SEG_OFF[s + 1]) s++;
    int local = i - SEG_OFF[s];
    const void* src = ptrs.p[s];
    cp[i] = flags[1] ? us2f(((const ushort*)src)[local]) : ((const float*)src)[local];
}

// ---------------- graph preprocessing ----------------

__global__ void k_init(int* __restrict__ deg, float* __restrict__ stats,
                       int* __restrict__ cursor, int2* __restrict__ srw) {
    int i = blockIdx.x * 256 + threadIdx.x;
    if (i < NN) deg[i] = 1;           // self-loop
    if (i < 768) stats[i] = 0.f;      // 3 layers x 256 stats
    if (i == 0) *cursor = 0;
    if (i < CAP) srw[i] = make_int2(0, 0);   // zero-weight sentinel edges (pad)
}

__global__ void k_deg(const int* __restrict__ ei, const int* __restrict__ flags,
                      int* __restrict__ deg) {
    int e = blockIdx.x * 256 + threadIdx.x;
    if (e < NE) atomicAdd(&deg[eidx(ei, flags[0], 1, e)], 1);
}

__global__ void k_dinv_alloc(const int* __restrict__ deg, float* __restrict__ dinv,
                             int* __restrict__ startA, int* __restrict__ curA,
                             int* __restrict__ cursor) {
    int i = blockIdx.x * 256 + threadIdx.x;
    if (i < NN) {
        int d = deg[i];
        dinv[i] = rsqrtf((float)d);
        int cpad = (d - 1 + 7) & ~7;        // pad each list to multiple of 8
        int s = atomicAdd(cursor, cpad);    // bucket order irrelevant for sums
        startA[i] = s;
        curA[i] = s;
    }
}

__global__ void k_fill(const int* __restrict__ ei, const int* __restrict__ flags,
                       const float* __restrict__ dinv, int* __restrict__ curA,
                       int2* __restrict__ srw) {
    int e = blockIdx.x * 256 + threadIdx.x;
    if (e >= NE) return;
    int isL = flags[0];
    int r = eidx(ei, isL, 0, e);
    int c = eidx(ei, isL, 1, e);
    int p = atomicAdd(&curA[c], 1);
    srw[p] = make_int2(r << 7, __float_as_int(dinv[r] * dinv[c]));
}

// ---------------- embed: relu(x @ coord_W + b) -> LayerNorm ----------------

__global__ void k_embed(const float* __restrict__ cp, float* __restrict__ h) {
    int node = (blockIdx.x * 256 + threadIdx.x) >> 6;
    int lane = threadIdx.x & 63;
    if (node >= NN) return;
    const float* X = cp + O_X;
    const float* CW = cp + O_CW;
    const float* CB = cp + O_CB;
    const float* LG = cp + O_LNG;
    const float* LB = cp + O_LNB;
    float x0 = X[node * 2], x1 = X[node * 2 + 1];
    int f0 = lane, f1 = lane + 64;
    float v0 = fmaxf(0.f, x0 * CW[f0] + x1 * CW[HD + f0] + CB[f0]);
    float v1 = fmaxf(0.f, x0 * CW[f1] + x1 * CW[HD + f1] + CB[f1]);
    float s = v0 + v1, q = v0 * v0 + v1 * v1;
    for (int o = 32; o; o >>= 1) { s += __shfl_xor(s, o); q += __shfl_xor(q, o); }
    float m = s * (1.f / HD);
    float var = q * (1.f / HD) - m * m;
    float r = rsqrtf(var + EPSN);
    h[(size_t)node * HD + f0] = (v0 - m) * r * LG[f0] + LB[f0];
    h[(size_t)node * HD + f1] = (v1 - m) * r * LG[f1] + LB[f1];
}

// ------- GEMM (layer 0): t0h = fp16(h @ W) -------
// 32 nodes/block, 256 threads, 16 outputs/thread (4 nodes x 4 feats), k-blocked by 4.

__global__ __launch_bounds__(256) void k_gemm(const float* __restrict__ h,
                                              const float* __restrict__ Wf,
                                              ushort* __restrict__ t0h) {
    __shared__ float Wl[64 * HD];       // 32 KB (one k-phase)
    __shared__ float hl[32 * HD];       // 16 KB
    int t = threadIdx.x;
    int nodeBase = blockIdx.x * 32;
    const float4* h4 = (const float4*)h;
    float4* hl4 = (float4*)hl;
#pragma unroll
    for (int r = 0; r < 4; r++) {
        int idx = r * 256 + t;          // 0..1023
        int n = nodeBase + (idx >> 5);  // global node
        int c4 = idx & 31;              // float4 col
        hl4[idx] = (n < NN) ? h4[(size_t)n * 32 + c4] : make_float4(0.f, 0.f, 0.f, 0.f);
    }
    int fq = t & 31;                    // feature quad: feats 4fq..4fq+3
    int ng = t >> 5;                    // node group 0..7; nodes ng, ng+8, ng+16, ng+24
    float4 acc[4];
#pragma unroll
    for (int j = 0; j < 4; j++) acc[j] = make_float4(0.f, 0.f, 0.f, 0.f);
    const float4* Wl4 = (const float4*)Wl;
    for (int ph = 0; ph < 2; ph++) {
        __syncthreads();                // hl ready (ph=0); prior-phase Wl reads done (ph=1)
        const float4* Wg4 = (const float4*)(Wf + ph * 64 * HD);
        float4* Wld = (float4*)Wl;
#pragma unroll
        for (int r = 0; r < 8; r++) Wld[r * 256 + t] = Wg4[r * 256 + t];
        __syncthreads();
        for (int k4 = 0; k4 < 16; k4++) {
            int kb = k4 * 4;
            float4 w0 = Wl4[(kb + 0) * 32 + fq];
            float4 w1 = Wl4[(kb + 1) * 32 + fq];
            float4 w2 = Wl4[(kb + 2) * 32 + fq];
            float4 w3 = Wl4[(kb + 3) * 32 + fq];
#pragma unroll
            for (int j = 0; j < 4; j++) {
                float4 hv = hl4[(ng + 8 * j) * 32 + ph * 16 + k4];
                acc[j].x += hv.x * w0.x + hv.y * w1.x + hv.z * w2.x + hv.w * w3.x;
                acc[j].y += hv.x * w0.y + hv.y * w1.y + hv.z * w2.y + hv.w * w3.y;
                acc[j].z += hv.x * w0.z + hv.y * w1.z + hv.z * w2.z + hv.w * w3.z;
                acc[j].w += hv.x * w0.w + hv.y * w1.w + hv.z * w2.w + hv.w * w3.w;
            }
        }
    }
#pragma unroll
    for (int j = 0; j < 4; j++) {
        int n = nodeBase + ng + 8 * j;
        if (n < NN) {
            ushort4 o;
            o.x = f2h(acc[j].x); o.y = f2h(acc[j].y);
            o.z = f2h(acc[j].z); o.w = f2h(acc[j].w);
            ((ushort4*)(t0h + (size_t)n * HD))[fq] = o;
        }
    }
}

// ------- fused BN+residual+InstanceNorm + GEMM (layers 1,2) -------
// staging computes u = instnorm(BN(relu(agg+bias)) + h) per node (32-lane shuffle
// reduction), writes u to h (next residual) and to LDS as the GEMM input tile.

__global__ __launch_bounds__(256) void k_gemm_fused(const float* __restrict__ agg,
                                                    const float* __restrict__ stats,
                                                    const float* __restrict__ bias,
                                                    const float* __restrict__ bng,
                                                    const float* __restrict__ bnb,
                                                    float* __restrict__ h,
                                                    const float* __restrict__ Wf,
                                                    ushort* __restrict__ t0h) {
    __shared__ float Wl[64 * HD];       // 32 KB
    __shared__ float hl[32 * HD];       // 16 KB
    __shared__ float scL[HD], shL[HD], bL[HD];
    int t = threadIdx.x;
    if (t < 128) {
        const float invN = 1.f / NN;
        float m = stats[t] * invN;
        float v = stats[128 + t] * invN - m * m;
        float sc = bng[t] * rsqrtf(v + EPSN);
        scL[t] = sc;
        shL[t] = bnb[t] - m * sc;
        bL[t] = bias[t];
    }
    __syncthreads();
    int nodeBase = blockIdx.x * 32;
    const float4* a4 = (const float4*)agg;
    float4* h4g = (float4*)h;
    float4* hl4 = (float4*)hl;
#pragma unroll
    for (int r = 0; r < 4; r++) {
        int idx = r * 256 + t;          // 0..1023
        int n = nodeBase + (idx >> 5);
        int c4 = idx & 31;
        float4 u = make_float4(0.f, 0.f, 0.f, 0.f);
        if (n < NN) {
            float4 av = a4[(size_t)n * 32 + c4];
            float4 hv = h4g[(size_t)n * 32 + c4];
            int f = c4 * 4;
            float y0 = fmaxf(0.f, av.x + bL[f]);
            float y1 = fmaxf(0.f, av.y + bL[f + 1]);
            float y2 = fmaxf(0.f, av.z + bL[f + 2]);
            float y3 = fmaxf(0.f, av.w + bL[f + 3]);
            u.x = y0 * scL[f]     + shL[f]     + hv.x;
            u.y = y1 * scL[f + 1] + shL[f + 1] + hv.y;
            u.z = y2 * scL[f + 2] + shL[f + 2] + hv.z;
            u.w = y3 * scL[f + 3] + shL[f + 3] + hv.w;
        }
        float s = u.x + u.y + u.z + u.w;
        float q = u.x * u.x + u.y * u.y + u.z * u.z + u.w * u.w;
        for (int o = 16; o; o >>= 1) { s += __shfl_xor(s, o); q += __shfl_xor(q, o); }
        float m = s * (1.f / HD);
        float var = q * (1.f / HD) - m * m;
        float rr = rsqrtf(var + EPSN);
        u.x = (u.x - m) * rr; u.y = (u.y - m) * rr;
        u.z = (u.z - m) * rr; u.w = (u.w - m) * rr;
        hl4[idx] = u;
        if (n < NN) h4g[(size_t)n * 32 + c4] = u;
    }
    int fq = t & 31;
    int ng = t >> 5;
    float4 acc[4];
#pragma unroll
    for (int j = 0; j < 4; j++) acc[j] = make_float4(0.f, 0.f, 0.f, 0.f);
    const float4* Wl4 = (const float4*)Wl;
    for (int ph = 0; ph < 2; ph++) {
        __syncthreads();
        const float4* Wg4 = (const float4*)(Wf + ph * 64 * HD);
        float4* Wld = (float4*)Wl;
#pragma unroll
        for (int r = 0; r < 8; r++) Wld[r * 256 + t] = Wg4[r * 256 + t];
        __syncthreads();
        for (int k4 = 0; k4 < 16; k4++) {
            int kb = k4 * 4;
            float4 w0 = Wl4[(kb + 0) * 32 + fq];
            float4 w1 = Wl4[(kb + 1) * 32 + fq];
            float4 w2 = Wl4[(kb + 2) * 32 + fq];
            float4 w3 = Wl4[(kb + 3) * 32 + fq];
#pragma unroll
            for (int j = 0; j < 4; j++) {
                float4 hv = hl4[(ng + 8 * j) * 32 + ph * 16 + k4];
                acc[j].x += hv.x * w0.x + hv.y * w1.x + hv.z * w2.x + hv.w * w3.x;
                acc[j].y += hv.x * w0.y + hv.y * w1.y + hv.z * w2.y + hv.w * w3.y;
                acc[j].z += hv.x * w0.z + hv.y * w1.z + hv.z * w2.z + hv.w * w3.z;
                acc[j].w += hv.x * w0.w + hv.y * w1.w + hv.z * w2.w + hv.w * w3.w;
            }
        }
    }
#pragma unroll
    for (int j = 0; j < 4; j++) {
        int n = nodeBase + ng + 8 * j;
        if (n < NN) {
            ushort4 o;
            o.x = f2h(acc[j].x); o.y = f2h(acc[j].y);
            o.z = f2h(acc[j].z); o.w = f2h(acc[j].w);
            ((ushort4*)(t0h + (size_t)n * HD))[fq] = o;
        }
    }
}

// ------- aggregate: agg[i] = dinv[i]^2*t0[i] + sum_in norm*t0[row]; fused BN stats -------
// 2 waves/node shape; padded CSR (lists multiple of 8, sentinel w=0) -> tail-free
// unroll-8 with 8 independent gathers in flight; one int2 index load per edge.

__global__ __launch_bounds__(256) void k_agg(const ushort* __restrict__ t0h,
                                             const int2* __restrict__ srw,
                                             const int* __restrict__ startA,
                                             const int* __restrict__ deg,
                                             const float* __restrict__ dinv,
                                             const float* __restrict__ bias,
                                             float* __restrict__ agg,
                                             float* __restrict__ stats) {
    int t = threadIdx.x;
    int f = t & 127;
    int half = t >> 7;
    float bs = bias[f];
    float rs1 = 0.f, rs2 = 0.f;
    for (int pair = blockIdx.x; pair * 2 < NN; pair += gridDim.x) {
        int i = pair * 2 + half;
        if (i < NN) {
            float di = dinv[i];
            float acc = di * di * h2f(t0h[i * HD + f]);   // self-loop term
            int s = startA[i];
            int cnt = deg[i] - 1;
            float a[8];
#pragma unroll
            for (int u = 0; u < 8; u++) a[u] = 0.f;
            for (int j = 0; j < cnt; j += 8) {            // padded: safe to read full batch
                int2 e[8];
#pragma unroll
                for (int u = 0; u < 8; u++) e[u] = srw[s + j + u];
                float g[8];
#pragma unroll
                for (int u = 0; u < 8; u++) g[u] = h2f(t0h[e[u].x + f]);
#pragma unroll
                for (int u = 0; u < 8; u++) a[u] += __int_as_float(e[u].y) * g[u];
            }
            acc += ((a[0] + a[1]) + (a[2] + a[3])) + ((a[4] + a[5]) + (a[6] + a[7]));
            agg[(size_t)i * HD + f] = acc;
            float y = fmaxf(0.f, acc + bs);
            rs1 += y;
            rs2 += y * y;
        }
    }
    __shared__ float l1[256], l2[256];
    l1[t] = rs1; l2[t] = rs2;
    __syncthreads();
    if (t < 128) {
        atomicAdd(&stats[t], l1[t] + l1[t + 128]);
        atomicAdd(&stats[128 + t], l2[t] + l2[t + 128]);
    }
}

// ------- BN apply + residual + InstanceNorm (layer 2 only, in-place on h) -------

__global__ void k_post(const float* __restrict__ agg, const float* __restrict__ stats,
                       const float* __restrict__ bias, const float* __restrict__ bng,
                       const float* __restrict__ bnb, float* __restrict__ h) {
    int node = (blockIdx.x * 256 + threadIdx.x) >> 6;
    int lane = threadIdx.x & 63;
    if (node >= NN) return;
    const float invN = 1.f / NN;
    int f0 = lane, f1 = lane + 64;
    float m0 = stats[f0] * invN, m1 = stats[f1] * invN;
    float v0 = stats[128 + f0] * invN - m0 * m0;
    float v1 = stats[128 + f1] * invN - m1 * m1;
    float sc0 = bng[f0] * rsqrtf(v0 + EPSN);
    float sc1 = bng[f1] * rsqrtf(v1 + EPSN);
    float sh0 = bnb[f0] - m0 * sc0;
    float sh1 = bnb[f1] - m1 * sc1;
    size_t base = (size_t)node * HD;
    float y0 = fmaxf(0.f, agg[base + f0] + bias[f0]);
    float y1 = fmaxf(0.f, agg[base + f1] + bias[f1]);
    float u0 = y0 * sc0 + sh0 + h[base + f0];
    float u1 = y1 * sc1 + sh1 + h[base + f1];
    float s = u0 + u1, q = u0 * u0 + u1 * u1;
    for (int o = 32; o; o >>= 1) { s += __shfl_xor(s, o); q += __shfl_xor(q, o); }
    float m = s * (1.f / HD);
    float var = q * (1.f / HD) - m * m;
    float r = rsqrtf(var + EPSN);
    h[base + f0] = (u0 - m) * r;
    h[base + f1] = (u1 - m) * r;
}

// ------- head: relu(h @ fc1 + b) -> tanh(@ fc2 + b); output dtype per flag -------

__global__ __launch_bounds__(256) void k_head(const float* __restrict__ h,
                                              const float* __restrict__ cp,
                                              const int* __restrict__ flags,
                                              void* __restrict__ outv) {
    __shared__ float W1[HD * 32];   // 16 KB, flat [k][f]
    __shared__ float B1[32], W2[64], B2[2];
    int t = threadIdx.x;
    const float* f1W = cp + O_F1W;
    for (int r = 0; r < 16; r++) W1[r * 256 + t] = f1W[r * 256 + t];
    if (t < 32) B1[t] = cp[O_F1B + t];
    if (t < 64) W2[t] = cp[O_F2W + t];
    if (t < 2) B2[t] = cp[O_F2B + t];
    __syncthreads();
    int i = blockIdx.x * 256 + t;
    if (i >= NN) return;
    float a[32];
#pragma unroll
    for (int f = 0; f < 32; f++) a[f] = B1[f];
    const float4* hr = (const float4*)(h + (size_t)i * HD);
    for (int c = 0; c < 4; c++) {
        float hk[32];
#pragma unroll
        for (int qd = 0; qd < 8; qd++) {
            float4 v = hr[c * 8 + qd];
            hk[4 * qd] = v.x; hk[4 * qd + 1] = v.y; hk[4 * qd + 2] = v.z; hk[4 * qd + 3] = v.w;
        }
#pragma unroll
        for (int kk = 0; kk < 32; kk++) {
            float hv = hk[kk];
            const float4* wr = (const float4*)(W1 + (c * 32 + kk) * 32);
#pragma unroll
            for (int qd = 0; qd < 8; qd++) {
                float4 w = wr[qd];
                a[4 * qd] += hv * w.x; a[4 * qd + 1] += hv * w.y;
                a[4 * qd + 2] += hv * w.z; a[4 * qd + 3] += hv * w.w;
            }
        }
    }
    float o0 = B2[0], o1 = B2[1];
#pragma unroll
    for (int f = 0; f < 32; f++) {
        float av = fmaxf(0.f, a[f]);
        o0 += av * W2[f * 2];
        o1 += av * W2[f * 2 + 1];
    }
    o0 = tanhf(o0); o1 = tanhf(o1);
    if (flags[1]) {
        ushort* ob = (ushort*)outv;
        ob[i * 2] = f2us(o0);
        ob[i * 2 + 1] = f2us(o1);
    } else {
        float* of = (float*)outv;
        of[i * 2] = o0;
        of[i * 2 + 1] = o1;
    }
}

// ---------------- launch ----------------

extern "C" void kernel_launch(void* const* d_in, const int* in_sizes, int n_in,
                              void* d_out, int out_size, void* d_ws, size_t ws_size,
                              hipStream_t stream) {
    const int* ei = (const int*)d_in[1];

    Ptrs ptrs;
    ptrs.p[0] = d_in[0];                                  // x
    for (int s = 1; s < 17; s++) ptrs.p[s] = d_in[s + 1]; // coord_W .. fc2_b

    char* wsp = (char*)d_ws;
    size_t off = 0;
    auto alloc = [&](size_t bytes) {
        void* p = wsp + off;
        off += (bytes + 255) & ~(size_t)255;
        return p;
    };
    float* cp     = (float*)alloc((size_t)O_TOT * 4);       // 0.62 MB canonical fp32 params
    float* h      = (float*)alloc((size_t)NN * HD * 4);     // 25.6 MB
    ushort* t0h   = (ushort*)alloc((size_t)NN * HD * 2);    // 12.8 MB fp16
    float* agg    = (float*)alloc((size_t)NN * HD * 4);     // 25.6 MB
    int* deg      = (int*)alloc((size_t)NN * 4);
    float* dinv   = (float*)alloc((size_t)NN * 4);
    int2* srw     = (int2*)alloc((size_t)CAP * 8);          // 9.2 MB padded CSR
    int* startA   = (int*)alloc((size_t)NN * 4);
    int* curA     = (int*)alloc((size_t)NN * 4);
    float* stats  = (float*)alloc(3 * 256 * 4);
    int* cursor   = (int*)alloc(256);
    int* flags    = (int*)alloc(256);

    const int BN_NODE = (NN + 255) / 256;   // 196
    const int BN_EDGE = (NE + 255) / 256;   // 3125
    const int BN_CONV = (O_TOT + 255) / 256;
    const int BN_CAP  = (CAP + 255) / 256;  // 4500

    const float* W[3] = {cp + O_W1, cp + O_W2, cp + O_W3};
    const float* B[3] = {cp + O_B1, cp + O_B2, cp + O_B3};

    k_detect<<<1, 256, 0, stream>>>(ei, (const ushort*)d_in[2], flags);
    k_conv<<<BN_CONV, 256, 0, stream>>>(ptrs, flags, cp);
    k_init<<<BN_CAP, 256, 0, stream>>>(deg, stats, cursor, srw);
    k_deg<<<BN_EDGE, 256, 0, stream>>>(ei, flags, deg);
    k_dinv_alloc<<<BN_NODE, 256, 0, stream>>>(deg, dinv, startA, curA, cursor);
    k_fill<<<BN_EDGE, 256, 0, stream>>>(ei, flags, dinv, curA, srw);
    k_embed<<<NN / 4, 256, 0, stream>>>(cp, h);

    k_gemm<<<(NN + 31) / 32, 256, 0, stream>>>(h, W[0], t0h);
    k_agg<<<2048, 256, 0, stream>>>(t0h, srw, startA, deg, dinv, B[0], agg, stats);
    for (int l = 1; l < 3; l++) {
        k_gemm_fused<<<(NN + 31) / 32, 256, 0, stream>>>(agg, stats + 256 * (l - 1),
                                                         B[l - 1], cp + O_BNG, cp + O_BNB,
                                                         h, W[l], t0h);
        k_agg<<<2048, 256, 0, stream>>>(t0h, srw, startA, deg, dinv, B[l],
                                        agg, stats + 256 * l);
    }
    k_post<<<NN / 4, 256, 0, stream>>>(agg, stats + 512, B[2], cp + O_BNG, cp + O_BNB, h);
    k_head<<<BN_NODE, 256, 0, stream>>>(h, cp, flags, d_out);
}

// Round 9
// 675.907 us; speedup vs baseline: 1.1985x; 1.0212x over previous
//
#include <hip/hip_runtime.h>
#include <hip/hip_bf16.h>
#include <hip/hip_fp16.h>
#include <stdint.h>

#define NN 50000
#define NE 800000
#define HD 128
#define EPSN 1e-5f
#define CAP 1152000   // padded CSR capacity: NE + NN*7 rounded up

typedef __hip_bfloat16 bf16;

__device__ __forceinline__ float us2f(unsigned short u) { return __uint_as_float((uint32_t)u << 16); }
__device__ __forceinline__ ushort f2us(float f) {
    bf16 b = __float2bfloat16(f);
    return *reinterpret_cast<ushort*>(&b);
}
__device__ __forceinline__ ushort f2h(float f) {
    __half h = __float2half(f);
    return *reinterpret_cast<ushort*>(&h);
}
__device__ __forceinline__ float h2f(ushort u) {
    __half h = *reinterpret_cast<__half*>(&u);
    return __half2float(h);
}

// canonical fp32 parameter block offsets
#define O_X    0
#define O_CW   100000
#define O_CB   100256
#define O_LNG  100384
#define O_LNB  100512
#define O_BNG  100640
#define O_BNB  100768
#define O_W1   100896
#define O_B1   117280
#define O_W2   117408
#define O_B2   133792
#define O_W3   133920
#define O_B3   150304
#define O_F1W  150432
#define O_F1B  154528
#define O_F2W  154560
#define O_F2B  154624
#define O_TOT  154626

struct Ptrs { const void* p[17]; };

__device__ const int SEG_OFF[18] = {O_X, O_CW, O_CB, O_LNG, O_LNB, O_BNG, O_BNB,
                                    O_W1, O_B1, O_W2, O_B2, O_W3, O_B3,
                                    O_F1W, O_F1B, O_F2W, O_F2B, O_TOT};

// Edge accessor: isL=1 -> int64 storage (read low words), else int32.
__device__ __forceinline__ int eidx(const int* __restrict__ ei, int isL, int which, int e) {
    size_t base = (size_t)which * NE + e;
    return isL ? ei[2 * base] : ei[base];
}

// ---------------- dtype detection ----------------
__global__ void k_detect(const int* __restrict__ ei, const ushort* __restrict__ cw,
                         int* __restrict__ flags) {
    int t = threadIdx.x;   // 256 threads, 1 block
    int v = ei[2 * t + 1] | ei[1000000 + 2 * t + 1];
    int bad = 0;
    if (t < 128) {
        float val = us2f(cw[2 * t]);           // low half if f32, real weight if bf16
        bad = !(fabsf(val) <= 1.0f);           // NaN/Inf -> bad
    }
    for (int o = 32; o; o >>= 1) { v |= __shfl_xor(v, o); bad |= __shfl_xor(bad, o); }
    __shared__ int sv[4], sb[4];
    if ((t & 63) == 0) { sv[t >> 6] = v; sb[t >> 6] = bad; }
    __syncthreads();
    if (t == 0) {
        flags[0] = ((sv[0] | sv[1] | sv[2] | sv[3]) == 0) ? 1 : 0;
        flags[1] = ((sb[0] | sb[1] | sb[2] | sb[3]) == 0) ? 1 : 0;
    }
}

// ---------------- canonicalize all float inputs to fp32 ----------------
__global__ void k_conv(Ptrs ptrs, const int* __restrict__ flags, float* __restrict__ cp) {
    int i = blockIdx.x * 256 + threadIdx.x;
    if (i >= O_TOT) return;
    int s = 0;
    while (i >= SEG_OFF[s + 1]) s++;
    int local = i - SEG_OFF[s];
    const void* src = ptrs.p[s];
    cp[i] = flags[1] ? us2f(((const ushort*)src)[local]) : ((const float*)src)[local];
}

// ---------------- graph preprocessing ----------------

__global__ void k_init(int* __restrict__ deg, float* __restrict__ stats,
                       int* __restrict__ cursor, int2* __restrict__ srw) {
    int i = blockIdx.x * 256 + threadIdx.x;
    if (i < NN) deg[i] = 1;           // self-loop
    if (i < 768) stats[i] = 0.f;      // 3 layers x 256 stats
    if (i == 0) *cursor = 0;
    if (i < CAP) srw[i] = make_int2(0, 0);   // zero-weight sentinel edges (pad)
}

__global__ void k_deg(const int* __restrict__ ei, const int* __restrict__ flags,
                      int* __restrict__ deg) {
    int e = blockIdx.x * 256 + threadIdx.x;
    if (e < NE) atomicAdd(&deg[eidx(ei, flags[0], 1, e)], 1);
}

__global__ void k_dinv_alloc(const int* __restrict__ deg, float* __restrict__ dinv,
                             int* __restrict__ startA, int* __restrict__ curA,
                             int* __restrict__ cursor) {
    int i = blockIdx.x * 256 + threadIdx.x;
    if (i < NN) {
        int d = deg[i];
        dinv[i] = rsqrtf((float)d);
        int cpad = (d - 1 + 7) & ~7;        // pad each list to multiple of 8
        int s = atomicAdd(cursor, cpad);    // bucket order irrelevant for sums
        startA[i] = s;
        curA[i] = s;
    }
}

__global__ void k_fill(const int* __restrict__ ei, const int* __restrict__ flags,
                       const float* __restrict__ dinv, int* __restrict__ curA,
                       int2* __restrict__ srw) {
    int e = blockIdx.x * 256 + threadIdx.x;
    if (e >= NE) return;
    int isL = flags[0];
    int r = eidx(ei, isL, 0, e);
    int c = eidx(ei, isL, 1, e);
    int p = atomicAdd(&curA[c], 1);
    srw[p] = make_int2(r << 7, __float_as_int(dinv[r] * dinv[c]));
}

// ---------------- embed: relu(x @ coord_W + b) -> LayerNorm ----------------

__global__ void k_embed(const float* __restrict__ cp, float* __restrict__ h) {
    int node = (blockIdx.x * 256 + threadIdx.x) >> 6;
    int lane = threadIdx.x & 63;
    if (node >= NN) return;
    const float* X = cp + O_X;
    const float* CW = cp + O_CW;
    const float* CB = cp + O_CB;
    const float* LG = cp + O_LNG;
    const float* LB = cp + O_LNB;
    float x0 = X[node * 2], x1 = X[node * 2 + 1];
    int f0 = lane, f1 = lane + 64;
    float v0 = fmaxf(0.f, x0 * CW[f0] + x1 * CW[HD + f0] + CB[f0]);
    float v1 = fmaxf(0.f, x0 * CW[f1] + x1 * CW[HD + f1] + CB[f1]);
    float s = v0 + v1, q = v0 * v0 + v1 * v1;
    for (int o = 32; o; o >>= 1) { s += __shfl_xor(s, o); q += __shfl_xor(q, o); }
    float m = s * (1.f / HD);
    float var = q * (1.f / HD) - m * m;
    float r = rsqrtf(var + EPSN);
    h[(size_t)node * HD + f0] = (v0 - m) * r * LG[f0] + LB[f0];
    h[(size_t)node * HD + f1] = (v1 - m) * r * LG[f1] + LB[f1];
}

// ------- GEMM (layer 0): t0h = fp16(h @ W) -------
// 32 nodes/block, 256 threads, 16 outputs/thread (4 nodes x 4 feats), k-blocked by 4.

__global__ __launch_bounds__(256) void k_gemm(const float* __restrict__ h,
                                              const float* __restrict__ Wf,
                                              ushort* __restrict__ t0h) {
    __shared__ float Wl[64 * HD];       // 32 KB (one k-phase)
    __shared__ float hl[32 * HD];       // 16 KB
    int t = threadIdx.x;
    int nodeBase = blockIdx.x * 32;
    const float4* h4 = (const float4*)h;
    float4* hl4 = (float4*)hl;
#pragma unroll
    for (int r = 0; r < 4; r++) {
        int idx = r * 256 + t;          // 0..1023
        int n = nodeBase + (idx >> 5);  // global node
        int c4 = idx & 31;              // float4 col
        hl4[idx] = (n < NN) ? h4[(size_t)n * 32 + c4] : make_float4(0.f, 0.f, 0.f, 0.f);
    }
    int fq = t & 31;                    // feature quad: feats 4fq..4fq+3
    int ng = t >> 5;                    // node group 0..7; nodes ng, ng+8, ng+16, ng+24
    float4 acc[4];
#pragma unroll
    for (int j = 0; j < 4; j++) acc[j] = make_float4(0.f, 0.f, 0.f, 0.f);
    const float4* Wl4 = (const float4*)Wl;
    for (int ph = 0; ph < 2; ph++) {
        __syncthreads();                // hl ready (ph=0); prior-phase Wl reads done (ph=1)
        const float4* Wg4 = (const float4*)(Wf + ph * 64 * HD);
        float4* Wld = (float4*)Wl;
#pragma unroll
        for (int r = 0; r < 8; r++) Wld[r * 256 + t] = Wg4[r * 256 + t];
        __syncthreads();
        for (int k4 = 0; k4 < 16; k4++) {
            int kb = k4 * 4;
            float4 w0 = Wl4[(kb + 0) * 32 + fq];
            float4 w1 = Wl4[(kb + 1) * 32 + fq];
            float4 w2 = Wl4[(kb + 2) * 32 + fq];
            float4 w3 = Wl4[(kb + 3) * 32 + fq];
#pragma unroll
            for (int j = 0; j < 4; j++) {
                float4 hv = hl4[(ng + 8 * j) * 32 + ph * 16 + k4];
                acc[j].x += hv.x * w0.x + hv.y * w1.x + hv.z * w2.x + hv.w * w3.x;
                acc[j].y += hv.x * w0.y + hv.y * w1.y + hv.z * w2.y + hv.w * w3.y;
                acc[j].z += hv.x * w0.z + hv.y * w1.z + hv.z * w2.z + hv.w * w3.z;
                acc[j].w += hv.x * w0.w + hv.y * w1.w + hv.z * w2.w + hv.w * w3.w;
            }
        }
    }
#pragma unroll
    for (int j = 0; j < 4; j++) {
        int n = nodeBase + ng + 8 * j;
        if (n < NN) {
            ushort4 o;
            o.x = f2h(acc[j].x); o.y = f2h(acc[j].y);
            o.z = f2h(acc[j].z); o.w = f2h(acc[j].w);
            ((ushort4*)(t0h + (size_t)n * HD))[fq] = o;
        }
    }
}

// ------- fused BN+residual+InstanceNorm + GEMM (layers 1,2) -------

__global__ __launch_bounds__(256) void k_gemm_fused(const float* __restrict__ agg,
                                                    const float* __restrict__ stats,
                                                    const float* __restrict__ bias,
                                                    const float* __restrict__ bng,
                                                    const float* __restrict__ bnb,
                                                    float* __restrict__ h,
                                                    const float* __restrict__ Wf,
                                                    ushort* __restrict__ t0h) {
    __shared__ float Wl[64 * HD];       // 32 KB
    __shared__ float hl[32 * HD];       // 16 KB
    __shared__ float scL[HD], shL[HD], bL[HD];
    int t = threadIdx.x;
    if (t < 128) {
        const float invN = 1.f / NN;
        float m = stats[t] * invN;
        float v = stats[128 + t] * invN - m * m;
        float sc = bng[t] * rsqrtf(v + EPSN);
        scL[t] = sc;
        shL[t] = bnb[t] - m * sc;
        bL[t] = bias[t];
    }
    __syncthreads();
    int nodeBase = blockIdx.x * 32;
    const float4* a4 = (const float4*)agg;
    float4* h4g = (float4*)h;
    float4* hl4 = (float4*)hl;
#pragma unroll
    for (int r = 0; r < 4; r++) {
        int idx = r * 256 + t;          // 0..1023
        int n = nodeBase + (idx >> 5);
        int c4 = idx & 31;
        float4 u = make_float4(0.f, 0.f, 0.f, 0.f);
        if (n < NN) {
            float4 av = a4[(size_t)n * 32 + c4];
            float4 hv = h4g[(size_t)n * 32 + c4];
            int f = c4 * 4;
            float y0 = fmaxf(0.f, av.x + bL[f]);
            float y1 = fmaxf(0.f, av.y + bL[f + 1]);
            float y2 = fmaxf(0.f, av.z + bL[f + 2]);
            float y3 = fmaxf(0.f, av.w + bL[f + 3]);
            u.x = y0 * scL[f]     + shL[f]     + hv.x;
            u.y = y1 * scL[f + 1] + shL[f + 1] + hv.y;
            u.z = y2 * scL[f + 2] + shL[f + 2] + hv.z;
            u.w = y3 * scL[f + 3] + shL[f + 3] + hv.w;
        }
        float s = u.x + u.y + u.z + u.w;
        float q = u.x * u.x + u.y * u.y + u.z * u.z + u.w * u.w;
        for (int o = 16; o; o >>= 1) { s += __shfl_xor(s, o); q += __shfl_xor(q, o); }
        float m = s * (1.f / HD);
        float var = q * (1.f / HD) - m * m;
        float rr = rsqrtf(var + EPSN);
        u.x = (u.x - m) * rr; u.y = (u.y - m) * rr;
        u.z = (u.z - m) * rr; u.w = (u.w - m) * rr;
        hl4[idx] = u;
        if (n < NN) h4g[(size_t)n * 32 + c4] = u;
    }
    int fq = t & 31;
    int ng = t >> 5;
    float4 acc[4];
#pragma unroll
    for (int j = 0; j < 4; j++) acc[j] = make_float4(0.f, 0.f, 0.f, 0.f);
    const float4* Wl4 = (const float4*)Wl;
    for (int ph = 0; ph < 2; ph++) {
        __syncthreads();
        const float4* Wg4 = (const float4*)(Wf + ph * 64 * HD);
        float4* Wld = (float4*)Wl;
#pragma unroll
        for (int r = 0; r < 8; r++) Wld[r * 256 + t] = Wg4[r * 256 + t];
        __syncthreads();
        for (int k4 = 0; k4 < 16; k4++) {
            int kb = k4 * 4;
            float4 w0 = Wl4[(kb + 0) * 32 + fq];
            float4 w1 = Wl4[(kb + 1) * 32 + fq];
            float4 w2 = Wl4[(kb + 2) * 32 + fq];
            float4 w3 = Wl4[(kb + 3) * 32 + fq];
#pragma unroll
            for (int j = 0; j < 4; j++) {
                float4 hv = hl4[(ng + 8 * j) * 32 + ph * 16 + k4];
                acc[j].x += hv.x * w0.x + hv.y * w1.x + hv.z * w2.x + hv.w * w3.x;
                acc[j].y += hv.x * w0.y + hv.y * w1.y + hv.z * w2.y + hv.w * w3.y;
                acc[j].z += hv.x * w0.z + hv.y * w1.z + hv.z * w2.z + hv.w * w3.z;
                acc[j].w += hv.x * w0.w + hv.y * w1.w + hv.z * w2.w + hv.w * w3.w;
            }
        }
    }
#pragma unroll
    for (int j = 0; j < 4; j++) {
        int n = nodeBase + ng + 8 * j;
        if (n < NN) {
            ushort4 o;
            o.x = f2h(acc[j].x); o.y = f2h(acc[j].y);
            o.z = f2h(acc[j].z); o.w = f2h(acc[j].w);
            ((ushort4*)(t0h + (size_t)n * HD))[fq] = o;
        }
    }
}

// ------- aggregate: agg[i] = dinv[i]^2*t0[i] + sum_in norm*t0[row]; fused BN stats -------
// 2 waves/node; padded tail-free CSR; software-pipelined: batch j's gathers issue
// FIRST, then batch j+1's index loads (FIFO vmcnt -> waiting on gathers keeps the
// prefetch outstanding), so gathers stay in flight across batch boundaries.

__global__ __launch_bounds__(256) void k_agg(const ushort* __restrict__ t0h,
                                             const int2* __restrict__ srw,
                                             const int* __restrict__ startA,
                                             const int* __restrict__ deg,
                                             const float* __restrict__ dinv,
                                             const float* __restrict__ bias,
                                             float* __restrict__ agg,
                                             float* __restrict__ stats) {
    int t = threadIdx.x;
    int f = t & 127;
    int half = t >> 7;
    float bs = bias[f];
    float rs1 = 0.f, rs2 = 0.f;
    for (int pair = blockIdx.x; pair * 2 < NN; pair += gridDim.x) {
        int i = pair * 2 + half;
        if (i < NN) {
            int s = startA[i];
            int cnt = deg[i] - 1;
            int nb = (cnt + 7) & ~7;          // padded batch count (sentinels w=0)
            int2 e[8];
            if (nb > 0) {
#pragma unroll
                for (int u = 0; u < 8; u++) e[u] = srw[s + u];
            }
            float di = dinv[i];
            float acc = di * di * h2f(t0h[i * HD + f]);   // self-loop term
            float a[8];
#pragma unroll
            for (int u = 0; u < 8; u++) a[u] = 0.f;
            for (int j = 0; j < nb; j += 8) {
                float g[8];
#pragma unroll
                for (int u = 0; u < 8; u++) g[u] = h2f(t0h[e[u].x + f]);   // gathers first
                int2 en[8];
                if (j + 8 < nb) {
#pragma unroll
                    for (int u = 0; u < 8; u++) en[u] = srw[s + j + 8 + u]; // prefetch next
                }
#pragma unroll
                for (int u = 0; u < 8; u++) a[u] += __int_as_float(e[u].y) * g[u];
                if (j + 8 < nb) {
#pragma unroll
                    for (int u = 0; u < 8; u++) e[u] = en[u];
                }
            }
            acc += ((a[0] + a[1]) + (a[2] + a[3])) + ((a[4] + a[5]) + (a[6] + a[7]));
            agg[(size_t)i * HD + f] = acc;
            float y = fmaxf(0.f, acc + bs);
            rs1 += y;
            rs2 += y * y;
        }
    }
    __shared__ float l1[256], l2[256];
    l1[t] = rs1; l2[t] = rs2;
    __syncthreads();
    if (t < 128) {
        atomicAdd(&stats[t], l1[t] + l1[t + 128]);
        atomicAdd(&stats[128 + t], l2[t] + l2[t + 128]);
    }
}

// ------- BN apply + residual + InstanceNorm (layer 2 only, in-place on h) -------

__global__ void k_post(const float* __restrict__ agg, const float* __restrict__ stats,
                       const float* __restrict__ bias, const float* __restrict__ bng,
                       const float* __restrict__ bnb, float* __restrict__ h) {
    int node = (blockIdx.x * 256 + threadIdx.x) >> 6;
    int lane = threadIdx.x & 63;
    if (node >= NN) return;
    const float invN = 1.f / NN;
    int f0 = lane, f1 = lane + 64;
    float m0 = stats[f0] * invN, m1 = stats[f1] * invN;
    float v0 = stats[128 + f0] * invN - m0 * m0;
    float v1 = stats[128 + f1] * invN - m1 * m1;
    float sc0 = bng[f0] * rsqrtf(v0 + EPSN);
    float sc1 = bng[f1] * rsqrtf(v1 + EPSN);
    float sh0 = bnb[f0] - m0 * sc0;
    float sh1 = bnb[f1] - m1 * sc1;
    size_t base = (size_t)node * HD;
    float y0 = fmaxf(0.f, agg[base + f0] + bias[f0]);
    float y1 = fmaxf(0.f, agg[base + f1] + bias[f1]);
    float u0 = y0 * sc0 + sh0 + h[base + f0];
    float u1 = y1 * sc1 + sh1 + h[base + f1];
    float s = u0 + u1, q = u0 * u0 + u1 * u1;
    for (int o = 32; o; o >>= 1) { s += __shfl_xor(s, o); q += __shfl_xor(q, o); }
    float m = s * (1.f / HD);
    float var = q * (1.f / HD) - m * m;
    float r = rsqrtf(var + EPSN);
    h[base + f0] = (u0 - m) * r;
    h[base + f1] = (u1 - m) * r;
}

// ------- head: relu(h @ fc1 + b) -> tanh(@ fc2 + b); output dtype per flag -------

__global__ __launch_bounds__(256) void k_head(const float* __restrict__ h,
                                              const float* __restrict__ cp,
                                              const int* __restrict__ flags,
                                              void* __restrict__ outv) {
    __shared__ float W1[HD * 32];   // 16 KB, flat [k][f]
    __shared__ float B1[32], W2[64], B2[2];
    int t = threadIdx.x;
    const float* f1W = cp + O_F1W;
    for (int r = 0; r < 16; r++) W1[r * 256 + t] = f1W[r * 256 + t];
    if (t < 32) B1[t] = cp[O_F1B + t];
    if (t < 64) W2[t] = cp[O_F2W + t];
    if (t < 2) B2[t] = cp[O_F2B + t];
    __syncthreads();
    int i = blockIdx.x * 256 + t;
    if (i >= NN) return;
    float a[32];
#pragma unroll
    for (int f = 0; f < 32; f++) a[f] = B1[f];
    const float4* hr = (const float4*)(h + (size_t)i * HD);
    for (int c = 0; c < 4; c++) {
        float hk[32];
#pragma unroll
        for (int qd = 0; qd < 8; qd++) {
            float4 v = hr[c * 8 + qd];
            hk[4 * qd] = v.x; hk[4 * qd + 1] = v.y; hk[4 * qd + 2] = v.z; hk[4 * qd + 3] = v.w;
        }
#pragma unroll
        for (int kk = 0; kk < 32; kk++) {
            float hv = hk[kk];
            const float4* wr = (const float4*)(W1 + (c * 32 + kk) * 32);
#pragma unroll
            for (int qd = 0; qd < 8; qd++) {
                float4 w = wr[qd];
                a[4 * qd] += hv * w.x; a[4 * qd + 1] += hv * w.y;
                a[4 * qd + 2] += hv * w.z; a[4 * qd + 3] += hv * w.w;
            }
        }
    }
    float o0 = B2[0], o1 = B2[1];
#pragma unroll
    for (int f = 0; f < 32; f++) {
        float av = fmaxf(0.f, a[f]);
        o0 += av * W2[f * 2];
        o1 += av * W2[f * 2 + 1];
    }
    o0 = tanhf(o0); o1 = tanhf(o1);
    if (flags[1]) {
        ushort* ob = (ushort*)outv;
        ob[i * 2] = f2us(o0);
        ob[i * 2 + 1] = f2us(o1);
    } else {
        float* of = (float*)outv;
        of[i * 2] = o0;
        of[i * 2 + 1] = o1;
    }
}

// ---------------- launch ----------------

extern "C" void kernel_launch(void* const* d_in, const int* in_sizes, int n_in,
                              void* d_out, int out_size, void* d_ws, size_t ws_size,
                              hipStream_t stream) {
    const int* ei = (const int*)d_in[1];

    Ptrs ptrs;
    ptrs.p[0] = d_in[0];                                  // x
    for (int s = 1; s < 17; s++) ptrs.p[s] = d_in[s + 1]; // coord_W .. fc2_b

    char* wsp = (char*)d_ws;
    size_t off = 0;
    auto alloc = [&](size_t bytes) {
        void* p = wsp + off;
        off += (bytes + 255) & ~(size_t)255;
        return p;
    };
    float* cp     = (float*)alloc((size_t)O_TOT * 4);       // 0.62 MB canonical fp32 params
    float* h      = (float*)alloc((size_t)NN * HD * 4);     // 25.6 MB
    ushort* t0h   = (ushort*)alloc((size_t)NN * HD * 2);    // 12.8 MB fp16
    float* agg    = (float*)alloc((size_t)NN * HD * 4);     // 25.6 MB
    int* deg      = (int*)alloc((size_t)NN * 4);
    float* dinv   = (float*)alloc((size_t)NN * 4);
    int2* srw     = (int2*)alloc((size_t)CAP * 8);          // 9.2 MB padded CSR
    int* startA   = (int*)alloc((size_t)NN * 4);
    int* curA     = (int*)alloc((size_t)NN * 4);
    float* stats  = (float*)alloc(3 * 256 * 4);
    int* cursor   = (int*)alloc(256);
    int* flags    = (int*)alloc(256);

    const int BN_NODE = (NN + 255) / 256;   // 196
    const int BN_EDGE = (NE + 255) / 256;   // 3125
    const int BN_CONV = (O_TOT + 255) / 256;
    const int BN_CAP  = (CAP + 255) / 256;  // 4500

    const float* W[3] = {cp + O_W1, cp + O_W2, cp + O_W3};
    const float* B[3] = {cp + O_B1, cp + O_B2, cp + O_B3};

    k_detect<<<1, 256, 0, stream>>>(ei, (const ushort*)d_in[2], flags);
    k_conv<<<BN_CONV, 256, 0, stream>>>(ptrs, flags, cp);
    k_init<<<BN_CAP, 256, 0, stream>>>(deg, stats, cursor, srw);
    k_deg<<<BN_EDGE, 256, 0, stream>>>(ei, flags, deg);
    k_dinv_alloc<<<BN_NODE, 256, 0, stream>>>(deg, dinv, startA, curA, cursor);
    k_fill<<<BN_EDGE, 256, 0, stream>>>(ei, flags, dinv, curA, srw);
    k_embed<<<NN / 4, 256, 0, stream>>>(cp, h);

    k_gemm<<<(NN + 31) / 32, 256, 0, stream>>>(h, W[0], t0h);
    k_agg<<<2048, 256, 0, stream>>>(t0h, srw, startA, deg, dinv, B[0], agg, stats);
    for (int l = 1; l < 3; l++) {
        k_gemm_fused<<<(NN + 31) / 32, 256, 0, stream>>>(agg, stats + 256 * (l - 1),
                                                         B[l - 1], cp + O_BNG, cp + O_BNB,
                                                         h, W[l], t0h);
        k_agg<<<2048, 256, 0, stream>>>(t0h, srw, startA, deg, dinv, B[l],
                                        agg, stats + 256 * l);
    }
    k_post<<<NN / 4, 256, 0, stream>>>(agg, stats + 512, B[2], cp + O_BNG, cp + O_BNB, h);
    k_head<<<BN_NODE, 256, 0, stream>>>(h, cp, flags, d_out);
}